// Round 5
// baseline (1397.008 us; speedup 1.0000x reference)
//
#include <hip/hip_runtime.h>

// =====================================================================
// DecoderLayer: selfMHA -> LN -> crossMHA -> LN -> 32xLSTM(pipelined)
//               -> pointwise conv -> LN
// Round 14: ILP attack on the serial chain. R9-R13 all expose ONE
//   dependency chain per wave (lanes=batches are lockstep); measured
//   marginal step cost 1.38k cyc vs ~400 theoretical. Now each wave
//   runs TWO batches as independent straight-line code (R13 lane
//   layout, weights shared -> 52 VGPR), so the compiler interleaves
//   two chains and hides the latency. Branch-free gate math (junk
//   lanes bounded-finite, stores predicated). Exact divisions in
//   sigmoid/tanh replaced by v_rcp_f32. Grid 512 blocks x 4 waves
//   (NGRP=16, BGRP=8): R9's proven lag-1 handoff, unchanged.
// =====================================================================

#define EPS_LN 1e-5f

typedef _Float16 h2v __attribute__((ext_vector_type(2)));
typedef _Float16 h8v __attribute__((ext_vector_type(8)));
typedef float    f4v __attribute__((ext_vector_type(4)));

#if defined(__has_builtin)
#if __has_builtin(__builtin_amdgcn_fdot2)
#define HAVE_FDOT2 1
#endif
#if __has_builtin(__builtin_amdgcn_rcpf)
#define HAVE_RCPF 1
#endif
#endif

__device__ __forceinline__ float fdot2(h2v a, h2v b, float c) {
#ifdef HAVE_FDOT2
  return __builtin_amdgcn_fdot2(a, b, c, false);
#else
  return c + (float)a.x * (float)b.x + (float)a.y * (float)b.y;
#endif
}
__device__ __forceinline__ h2v bch2(unsigned int u) {
  return __builtin_bit_cast(h2v, u);
}
__device__ __forceinline__ float rcp_fast(float x) {
#ifdef HAVE_RCPF
  return __builtin_amdgcn_rcpf(x);
#else
  return 1.f / x;
#endif
}
__device__ __forceinline__ float sigm_fast(float x) {
  return rcp_fast(1.f + __expf(-x));
}
__device__ __forceinline__ float tanh_fast(float x) {
  return 1.f - 2.f * rcp_fast(1.f + __expf(2.f * x));
}

// ---------------- fused weight prep: 8 transposes + 1 straight cvt -------
struct WPtrs { const float* p[9]; };

__global__ __launch_bounds__(256)
void prep_weights(WPtrs w, _Float16* __restrict__ dst) {
  __shared__ float tile[32][33];
  const int z = blockIdx.z;
  const int tx = threadIdx.x & 31, ty = threadIdx.x >> 5;
  const int bx = blockIdx.x, by = blockIdx.y;
  const float* in = w.p[z];
  _Float16* outp = dst + (size_t)z * 262144;
  if (z < 8) {
#pragma unroll
    for (int i = 0; i < 4; i++)
      tile[ty + i * 8][tx] = in[(size_t)(by * 32 + ty + i * 8) * 512 + bx * 32 + tx];
    __syncthreads();
#pragma unroll
    for (int i = 0; i < 4; i++)
      outp[(size_t)(bx * 32 + ty + i * 8) * 512 + by * 32 + tx] = (_Float16)tile[tx][ty + i * 8];
  } else {
#pragma unroll
    for (int i = 0; i < 4; i++) {
      size_t off = (size_t)(by * 32 + ty + i * 8) * 512 + bx * 32 + tx;
      outp[off] = (_Float16)in[off];
    }
  }
}

// ---------------- f16 MFMA GEMM, fp32 A staged+converted in LDS ----------
__global__ __launch_bounds__(256)
void gemm3(const float* __restrict__ A,
           const _Float16* __restrict__ BT0, const _Float16* __restrict__ BT1,
           const _Float16* __restrict__ BT2,
           const float* __restrict__ bias0, const float* __restrict__ bias1,
           const float* __restrict__ bias2,
           float* __restrict__ C0, float* __restrict__ C1, float* __restrict__ C2,
           int M) {
  __shared__ _Float16 Asld[64 * 40];
  __shared__ _Float16 Bsld[64 * 40];
  const int t = threadIdx.x;
  const int which = blockIdx.x >> 3;
  const int n0 = (blockIdx.x & 7) * 64;
  const int m0 = blockIdx.y * 64;
  const _Float16* BT = (which == 0) ? BT0 : (which == 1) ? BT1 : BT2;
  const float* bias  = (which == 0) ? bias0 : (which == 1) ? bias1 : bias2;
  float* C           = (which == 0) ? C0 : (which == 1) ? C1 : C2;

  const int r = t >> 2, q = t & 3;
  const int w = t >> 6;
  const int lane = t & 63;
  const int lm = lane & 15, q8 = lane >> 4;

  f4v acc[4] = {};
  for (int k0 = 0; k0 < 512; k0 += 32) {
    __syncthreads();
    float4 f0 = *(const float4*)&A[(size_t)(m0 + r) * 512 + k0 + q * 8];
    float4 f1 = *(const float4*)&A[(size_t)(m0 + r) * 512 + k0 + q * 8 + 4];
    h8v hvv = {(_Float16)f0.x, (_Float16)f0.y, (_Float16)f0.z, (_Float16)f0.w,
               (_Float16)f1.x, (_Float16)f1.y, (_Float16)f1.z, (_Float16)f1.w};
    *(h8v*)&Asld[r * 40 + q * 8] = hvv;
    *(uint4*)&Bsld[r * 40 + q * 8] = *(const uint4*)&BT[(size_t)(n0 + r) * 512 + k0 + q * 8];
    __syncthreads();
    h8v a = *(const h8v*)&Asld[(w * 16 + lm) * 40 + q8 * 8];
#pragma unroll
    for (int nt = 0; nt < 4; nt++) {
      h8v b = *(const h8v*)&Bsld[(nt * 16 + lm) * 40 + q8 * 8];
      acc[nt] = __builtin_amdgcn_mfma_f32_16x16x32_f16(a, b, acc[nt], 0, 0, 0);
    }
  }
#pragma unroll
  for (int nt = 0; nt < 4; nt++) {
    int gn = n0 + nt * 16 + lm;
    float bv = bias[gn];
#pragma unroll
    for (int rg = 0; rg < 4; rg++) {
      int gm = m0 + w * 16 + q8 * 4 + rg;
      C[(size_t)gm * 512 + gn] = acc[nt][rg] + bv;
    }
  }
}

// ---------------- attention: scores then softmax+PV, per (b,h) -----------
template <int S>
__global__ __launch_bounds__(256)
void attn_scores(const float* __restrict__ Q, const float* __restrict__ K,
                 float* __restrict__ P) {
  __shared__ float Qs[25][64];
  __shared__ float Ks[S][65];
  const int h = blockIdx.x, b = blockIdx.y, t = threadIdx.x;
  for (int idx = t; idx < 25 * 64; idx += 256) {
    int l = idx >> 6, e = idx & 63;
    Qs[l][e] = Q[(b * 25 + l) * 512 + h * 64 + e];
  }
  for (int idx = t; idx < S * 64; idx += 256) {
    int s = idx >> 6, e = idx & 63;
    Ks[s][e] = K[(b * S + s) * 512 + h * 64 + e];
  }
  __syncthreads();
  float* Pb = P + (size_t)(b * 8 + h) * 25 * S;
  for (int idx = t; idx < 25 * S; idx += 256) {
    int l = idx / S, s = idx % S;
    float acc = 0.f;
#pragma unroll
    for (int e = 0; e < 64; e++) acc += Qs[l][e] * Ks[s][e];
    Pb[idx] = acc * 0.125f;
  }
}

template <int S>
__global__ __launch_bounds__(256)
void attn_out(const float* __restrict__ P, const float* __restrict__ V,
              float* __restrict__ O) {
  __shared__ float Ps[25][S];
  __shared__ float Vs[S][64];
  const int h = blockIdx.x, b = blockIdx.y, t = threadIdx.x;
  const float* Pb = P + (size_t)(b * 8 + h) * 25 * S;
  for (int idx = t; idx < 25 * S; idx += 256) Ps[idx / S][idx % S] = Pb[idx];
  for (int idx = t; idx < S * 64; idx += 256) {
    int s = idx >> 6, e = idx & 63;
    Vs[s][e] = V[(b * S + s) * 512 + h * 64 + e];
  }
  __syncthreads();
  if (t < 25) {
    float mx = -1e30f;
    for (int s = 0; s < S; s++) mx = fmaxf(mx, Ps[t][s]);
    float sum = 0.f;
    for (int s = 0; s < S; s++) { float p = __expf(Ps[t][s] - mx); Ps[t][s] = p; sum += p; }
    float r = 1.f / sum;
    for (int s = 0; s < S; s++) Ps[t][s] *= r;
  }
  __syncthreads();
  for (int idx = t; idx < 25 * 64; idx += 256) {
    int l = idx >> 6, e = idx & 63;
    float acc = 0.f;
    for (int s = 0; s < S; s++) acc += Ps[l][s] * Vs[s][e];
    O[(b * 25 + l) * 512 + h * 64 + e] = acc;
  }
}

// ---------------- fused residual-add + LayerNorm (rows of 512) -----------
__global__ __launch_bounds__(128)
void add_ln(const float* __restrict__ a, const float* __restrict__ b,
            const float* __restrict__ gw, const float* __restrict__ bw,
            float* __restrict__ out) {
  const int row = blockIdx.x, t = threadIdx.x;
  float4 va = ((const float4*)(a + (size_t)row * 512))[t];
  float4 vb = ((const float4*)(b + (size_t)row * 512))[t];
  float4 v = make_float4(va.x + vb.x, va.y + vb.y, va.z + vb.z, va.w + vb.w);
  float s = v.x + v.y + v.z + v.w;
  float q = v.x * v.x + v.y * v.y + v.z * v.z + v.w * v.w;
#pragma unroll
  for (int off = 32; off > 0; off >>= 1) {
    s += __shfl_down(s, off);
    q += __shfl_down(q, off);
  }
  __shared__ float red[4];
  if ((t & 63) == 0) { red[(t >> 6) * 2] = s; red[(t >> 6) * 2 + 1] = q; }
  __syncthreads();
  float S_ = red[0] + red[2], Q_ = red[1] + red[3];
  float mean = S_ * (1.f / 512.f);
  float var  = Q_ * (1.f / 512.f) - mean * mean;
  float inv  = rsqrtf(var + EPS_LN);
  float4 g4 = ((const float4*)gw)[t];
  float4 b4 = ((const float4*)bw)[t];
  float4 o;
  o.x = (v.x - mean) * inv * g4.x + b4.x;
  o.y = (v.y - mean) * inv * g4.y + b4.y;
  o.z = (v.z - mean) * inv * g4.z + b4.z;
  o.w = (v.w - mean) * inv * g4.w + b4.w;
  ((float4*)(out + (size_t)row * 512))[t] = o;
}

// ---------------- transposes / LSTM preps --------------------------------
__global__ void transpose_dl(const float* __restrict__ in, float* __restrict__ outp) {
  const int b = blockIdx.x, t = threadIdx.x;
  for (int idx = t; idx < 25 * 512; idx += 256) {
    int l2 = idx / 512, c = idx % 512;
    outp[((size_t)b * 25 + l2) * 512 + c] = in[((size_t)b * 512 + c) * 25 + l2];
  }
}

// X0[b][t=512][32] f16 from x2[b][25][512] (u>=25 pads = 0)
__global__ __launch_bounds__(256)
void prep_x0r(const float* __restrict__ x2, _Float16* __restrict__ X0) {
  __shared__ float tile[25][516];
  const int b = blockIdx.x, t = threadIdx.x;
  for (int idx = t; idx < 25 * 512; idx += 256) {
    int u = idx >> 9, d = idx & 511;
    tile[u][d] = x2[((size_t)b * 25 + u) * 512 + d];
  }
  __syncthreads();
  for (int idx = t; idx < 512 * 32; idx += 256) {
    int d = idx >> 5, u = idx & 31;
    X0[((size_t)b * 512 + d) * 32 + u] = (u < 25) ? (_Float16)tile[u][d] : (_Float16)0.f;
  }
}

// ---------------- pipelined 32-layer LSTM (fdot2, wave-autonomous) -------
// R14: 512 blocks (32 layers x 16 groups of 8 batches), 256 thr = 4 waves.
// Each wave runs TWO batches as independent straight-line code (two
// dependency chains interleaved by the scheduler). Per batch: 64-lane
// R13 gate layout (lane L<50 rows {L,L+50}; lane u<25 unit u; sigma(f),
// sigma(o) via shuffles). Weights shared between the wave's batches.
// R9 lag-1 handoff protocol unchanged.
#define NLAY 32
#define NGRP 16
#define BGRP 8
#define CHT  8
#define NCHK 64
#define RSLOTS 64
#define RCHK (RSLOTS / CHT)
#define RLAY ((size_t)128 * RSLOTS * 32)   // halves per layer region

__device__ __forceinline__ int ld_rlx(int* p) {
  return __hip_atomic_load(p, __ATOMIC_RELAXED, __HIP_MEMORY_SCOPE_AGENT);
}
__device__ __forceinline__ void st_rlx(int* p, int v) {
  __hip_atomic_store(p, v, __ATOMIC_RELAXED, __HIP_MEMORY_SCOPE_AGENT);
}
__device__ __forceinline__ unsigned long long ldq_rlx(const unsigned long long* p) {
  return __hip_atomic_load(p, __ATOMIC_RELAXED, __HIP_MEMORY_SCOPE_AGENT);
}
__device__ __forceinline__ void sth_rlx(_Float16* p, _Float16 v) {
  __hip_atomic_store((unsigned short*)p, __builtin_bit_cast(unsigned short, v),
                     __ATOMIC_RELAXED, __HIP_MEMORY_SCOPE_AGENT);
}

__global__ __launch_bounds__(256) __attribute__((amdgpu_waves_per_eu(2, 2)))
void lstm_pipeline(const _Float16* __restrict__ X0, float* __restrict__ yout,
                   _Float16* __restrict__ ring, int* __restrict__ prod,
                   int* __restrict__ cons,
                   const float* __restrict__ Wih, const float* __restrict__ Whh,
                   const float* __restrict__ bih, const float* __restrict__ bhh) {
  const int l = blockIdx.x / NGRP;
  const int g = blockIdx.x % NGRP;
  const int t = threadIdx.x;
  const int lane = t & 63;
  const int wv   = t >> 6;               // wave 0..3
  const int bA   = wv * 2;               // wave's batch slots in block
  const int bB   = wv * 2 + 1;

  __shared__ _Float16 xbuf[CHT][BGRP][32];  // chunk input (4 KB)
  __shared__ _Float16 hbuf[BGRP][32];       // per-batch h (wave-private)

  // ---- weights packed half2: rows {lane, lane+50}, shared by A,B --------
  h2v wih2[2][13], whh2[2][13];
  float bias_r[2];
  float cA = 0.f, cB = 0.f;
  {
    const int r0 = (lane < 50) ? lane : 49;
#pragma unroll
    for (int j = 0; j < 2; j++) {
      const int row = r0 + j * 50;
      const float* wi = &Wih[((size_t)l * 100 + row) * 25];
      const float* wh = &Whh[((size_t)l * 100 + row) * 25];
#pragma unroll
      for (int k = 0; k < 13; k++) {
        float alo = wi[2 * k], ahi = (2 * k + 1 < 25) ? wi[2 * k + 1] : 0.f;
        float blo = wh[2 * k], bhi = (2 * k + 1 < 25) ? wh[2 * k + 1] : 0.f;
        wih2[j][k] = h2v{(_Float16)alo, (_Float16)ahi};
        whh2[j][k] = h2v{(_Float16)blo, (_Float16)bhi};
      }
      bias_r[j] = bih[l * 100 + row] + bhh[l * 100 + row];
    }
  }
  for (int idx = t; idx < BGRP * 32; idx += 256) (&hbuf[0][0])[idx] = (_Float16)0.f;
  __syncthreads();

  // producer out pointers
  const int gbA = g * BGRP + bA, gbB = g * BGRP + bB;
  _Float16* ring_outA = ring + (size_t)l * RLAY + ((size_t)gbA * RSLOTS) * 32 + lane;
  _Float16* ring_outB = ring + (size_t)l * RLAY + ((size_t)gbB * RSLOTS) * 32 + lane;
  float* yout_outA = yout + ((size_t)gbA * 512) * 25 + lane;
  float* yout_outB = yout + ((size_t)gbB * 512) * 25 + lane;

  // staging mapping: thread -> (tc, batch, 8-half segment); 16B per thread
  const int s_tc = t >> 5, s_b2 = (t >> 2) & 7, s_seg = t & 3;

  int* prod_in   = prod + (l - 1) * NGRP + g;   // valid only when l > 0
  int* prod_out  = prod + l * NGRP + g;         // valid only when l < NLAY-1
  int* cons_self = cons + l * NGRP + g;         // valid only when l > 0
  int* cons_up   = cons + (l + 1) * NGRP + g;   // valid only when l < NLAY-1

  for (int n = 0; n < NCHK; n++) {
    if (t == 0) {
      if (l > 0) {
        while (ld_rlx(prod_in) < n + 1) __builtin_amdgcn_s_sleep(1);
      }
      if (l < NLAY - 1 && n >= RCHK) {
        while (ld_rlx(cons_up) < n - RCHK + 1) __builtin_amdgcn_s_sleep(1);
      }
    }
    __syncthreads();                                   // (A) poll done
    // ---- stage chunk: ONE 16B load per thread ----
    {
      const int tg = n * CHT + s_tc;
      if (l == 0) {
        const uint4* p = (const uint4*)(X0
            + (((size_t)(g * BGRP + s_b2) * 512) + tg) * 32 + s_seg * 8);
        *(uint4*)&xbuf[s_tc][s_b2][s_seg * 8] = *p;
      } else {
        const unsigned long long* p = (const unsigned long long*)(ring
            + (size_t)(l - 1) * RLAY
            + (((size_t)(g * BGRP + s_b2) * RSLOTS) + (tg & (RSLOTS - 1))) * 32
            + s_seg * 8);
        unsigned long long a = ldq_rlx(p);
        unsigned long long b = ldq_rlx(p + 1);
        *(uint4*)&xbuf[s_tc][s_b2][s_seg * 8] =
            make_uint4((unsigned)a, (unsigned)(a >> 32),
                       (unsigned)b, (unsigned)(b >> 32));
      }
    }
    __syncthreads();                                   // (B) staging visible
    if (t == 0 && l > 0) st_rlx(cons_self, n + 1);

    // ---- x-part for all 8 steps, both batches (branch-free) ----
    float axA[CHT][2], axB[CHT][2];
#pragma unroll
    for (int tc = 0; tc < CHT; tc++) {
      const unsigned int* xrA = (const unsigned int*)&xbuf[tc][bA][0];
      const unsigned int* xrB = (const unsigned int*)&xbuf[tc][bB][0];
      uint4 xaA = *(const uint4*)(xrA);
      uint4 xbA = *(const uint4*)(xrA + 4);
      uint4 xcA = *(const uint4*)(xrA + 8);
      unsigned int xdA = xrA[12];
      uint4 xaB = *(const uint4*)(xrB);
      uint4 xbB = *(const uint4*)(xrB + 4);
      uint4 xcB = *(const uint4*)(xrB + 8);
      unsigned int xdB = xrB[12];
      h2v xkA[13] = {bch2(xaA.x), bch2(xaA.y), bch2(xaA.z), bch2(xaA.w),
                     bch2(xbA.x), bch2(xbA.y), bch2(xbA.z), bch2(xbA.w),
                     bch2(xcA.x), bch2(xcA.y), bch2(xcA.z), bch2(xcA.w),
                     bch2(xdA)};
      h2v xkB[13] = {bch2(xaB.x), bch2(xaB.y), bch2(xaB.z), bch2(xaB.w),
                     bch2(xbB.x), bch2(xbB.y), bch2(xbB.z), bch2(xbB.w),
                     bch2(xcB.x), bch2(xcB.y), bch2(xcB.z), bch2(xcB.w),
                     bch2(xdB)};
      float a0A = bias_r[0], a1A = bias_r[1];
      float a0B = bias_r[0], a1B = bias_r[1];
#pragma unroll
      for (int k = 0; k < 13; k++) {
        a0A = fdot2(wih2[0][k], xkA[k], a0A);
        a1A = fdot2(wih2[1][k], xkA[k], a1A);
        a0B = fdot2(wih2[0][k], xkB[k], a0B);
        a1B = fdot2(wih2[1][k], xkB[k], a1B);
      }
      axA[tc][0] = a0A; axA[tc][1] = a1A;
      axB[tc][0] = a0B; axB[tc][1] = a1B;
    }

    // ---- serial h-recurrence: 8 steps, two chains interleaved ----
#pragma unroll
    for (int tc = 0; tc < CHT; tc++) {
      const int tg = n * CHT + tc;
      // --- chain A gates ---
      const unsigned int* hrA = (const unsigned int*)&hbuf[bA][0];
      uint4 haA = *(const uint4*)(hrA);
      uint4 hbA_ = *(const uint4*)(hrA + 4);
      uint4 hcA = *(const uint4*)(hrA + 8);
      unsigned int hdA = hrA[12];
      h2v hkA[13] = {bch2(haA.x), bch2(haA.y), bch2(haA.z), bch2(haA.w),
                     bch2(hbA_.x), bch2(hbA_.y), bch2(hbA_.z), bch2(hbA_.w),
                     bch2(hcA.x), bch2(hcA.y), bch2(hcA.z), bch2(hcA.w),
                     bch2(hdA)};
      float a0A = axA[tc][0], a1A = axA[tc][1];
      // --- chain B gates ---
      const unsigned int* hrB = (const unsigned int*)&hbuf[bB][0];
      uint4 haB = *(const uint4*)(hrB);
      uint4 hbB_ = *(const uint4*)(hrB + 4);
      uint4 hcB = *(const uint4*)(hrB + 8);
      unsigned int hdB = hrB[12];
      h2v hkB[13] = {bch2(haB.x), bch2(haB.y), bch2(haB.z), bch2(haB.w),
                     bch2(hbB_.x), bch2(hbB_.y), bch2(hbB_.z), bch2(hbB_.w),
                     bch2(hcB.x), bch2(hcB.y), bch2(hcB.z), bch2(hcB.w),
                     bch2(hdB)};
      float a0B = axB[tc][0], a1B = axB[tc][1];
#pragma unroll
      for (int k = 0; k < 13; k++) {
        a0A = fdot2(whh2[0][k], hkA[k], a0A);
        a1A = fdot2(whh2[1][k], hkA[k], a1A);
        a0B = fdot2(whh2[0][k], hkB[k], a0B);
        a1B = fdot2(whh2[1][k], hkB[k], a1B);
      }
      // lane u<25: a0 = i_u, a1 = g_u.  lane 25+u: a0 = f_u, a1 = o_u.
      float s0A  = sigm_fast(a0A);
      float sg1A = sigm_fast(a1A);
      float th1A = tanh_fast(a1A);
      float s0B  = sigm_fast(a0B);
      float sg1B = sigm_fast(a1B);
      float th1B = tanh_fast(a1B);
      float sfA = __shfl(s0A,  lane + 25);
      float soA = __shfl(sg1A, lane + 25);
      float sfB = __shfl(s0B,  lane + 25);
      float soB = __shfl(sg1B, lane + 25);
      cA = sfA * cA + s0A * th1A;
      cB = sfB * cB + s0B * th1B;
      float hA = soA * tanh_fast(cA);
      float hB = soB * tanh_fast(cB);
      _Float16 hA16 = (_Float16)hA;
      _Float16 hB16 = (_Float16)hB;
      if (lane < 32) {              // junk lanes 25..31 bounded; x0 weights
        hbuf[bA][lane] = hA16;
        hbuf[bB][lane] = hB16;
      }
      if (lane < 25) {
        if (l == NLAY - 1) {
          yout_outA[(size_t)tg * 25] = hA;
          yout_outB[(size_t)tg * 25] = hB;
        } else {
          sth_rlx(ring_outA + (size_t)(tg & (RSLOTS - 1)) * 32, hA16);
          sth_rlx(ring_outB + (size_t)(tg & (RSLOTS - 1)) * 32, hB16);
        }
      }
    }
    asm volatile("s_waitcnt vmcnt(0)" ::: "memory");   // ring stores at MALL
    __syncthreads();                                   // (C) all waves done
    if (t == 0 && l < NLAY - 1) st_rlx(prod_out, n + 1);
  }
}

// =====================================================================
extern "C" void kernel_launch(void* const* d_in, const int* in_sizes, int n_in,
                              void* d_out, int out_size, void* d_ws, size_t ws_size,
                              hipStream_t stream) {
  const float* x     = (const float*)d_in[0];
  const float* cross = (const float*)d_in[1];
  const float* Wq_s = (const float*)d_in[2];  const float* bq_s = (const float*)d_in[3];
  const float* Wk_s = (const float*)d_in[4];  const float* bk_s = (const float*)d_in[5];
  const float* Wv_s = (const float*)d_in[6];  const float* bv_s = (const float*)d_in[7];
  const float* Wo_s = (const float*)d_in[8];  const float* bo_s = (const float*)d_in[9];
  const float* Wq_c = (const float*)d_in[10]; const float* bq_c = (const float*)d_in[11];
  const float* Wk_c = (const float*)d_in[12]; const float* bk_c = (const float*)d_in[13];
  const float* Wv_c = (const float*)d_in[14]; const float* bv_c = (const float*)d_in[15];
  const float* Wo_c = (const float*)d_in[16]; const float* bo_c = (const float*)d_in[17];
  const float* g1 = (const float*)d_in[18]; const float* b1 = (const float*)d_in[19];
  const float* g2 = (const float*)d_in[20]; const float* b2 = (const float*)d_in[21];
  const float* g3 = (const float*)d_in[22]; const float* b3 = (const float*)d_in[23];
  const float* Wih = (const float*)d_in[24];
  const float* Whh = (const float*)d_in[25];
  const float* bih = (const float*)d_in[26];
  const float* bhh = (const float*)d_in[27];
  const float* Wc  = (const float*)d_in[28]; const float* bc = (const float*)d_in[29];
  float* out = (float*)d_out;
  float* ws  = (float*)d_ws;

  // ---- workspace (floats); time-multiplexed regions ---------------------
  constexpr size_t A  = 1638400;    // 3200*512
  constexpr size_t C6 = 6291456;    // 12288*512
  float* x1    = ws;
  float* Qc    = ws + A;
  // self phase
  float* Qs    = ws + 2 * A;
  float* Ks    = ws + 3 * A;
  float* Vs    = ws + 4 * A;
  float* attns = ws + 5 * A;
  float* tmp   = ws + 6 * A;
  float* Ps    = ws + 7 * A;
  // cross phase
  float* Kc    = ws + 2 * A;
  float* Vc    = ws + 2 * A + C6;
  float* attnc = ws + 2 * A + 2 * C6;
  float* Pc    = attnc + A;
  float* tmp2  = ws + 6 * A;
  float* x2    = ws + 3 * A;
  // lstm / post
  _Float16* X0b  = (_Float16*)(ws + 4 * A);      // 128*512*32 halves = 1.05M fl
  float*    youtb = ws + 5 * A;                  // [128][512][25] fp32
  _Float16* ringb = (_Float16*)(ws + 6 * A);     // 31*RLAY = 8.13M halves
  float* ytb   = ws + 2 * A;
  float* fy    = ws + 5 * A;                     // after youtb dead
  _Float16* WTall = (_Float16*)(ws + 20000000);
  int* ctr = (int*)(ws + 21179648);

  dim3 blk(256);
  WPtrs wpq;
  wpq.p[0] = Wq_s; wpq.p[1] = Wk_s; wpq.p[2] = Wv_s; wpq.p[3] = Wo_s;
  wpq.p[4] = Wq_c; wpq.p[5] = Wk_c; wpq.p[6] = Wv_c; wpq.p[7] = Wo_c;
  wpq.p[8] = Wc;
  prep_weights<<<dim3(16, 16, 9), blk, 0, stream>>>(wpq, WTall);
  hipMemsetAsync(ctr, 0, 1024 * sizeof(int), stream);
  _Float16* WT[9];
  for (int i = 0; i < 9; i++) WT[i] = WTall + (size_t)i * 262144;

  // ---- self attention ----
  gemm3<<<dim3(24, 50), blk, 0, stream>>>(x, WT[0], WT[1], WT[2],
                                          bq_s, bk_s, bv_s, Qs, Ks, Vs, 3200);
  attn_scores<25><<<dim3(8, 128), blk, 0, stream>>>(Qs, Ks, Ps);
  attn_out<25><<<dim3(8, 128), blk, 0, stream>>>(Ps, Vs, attns);
  gemm3<<<dim3(8, 50), blk, 0, stream>>>(attns, WT[3], WT[3], WT[3],
                                         bo_s, bo_s, bo_s, tmp, tmp, tmp, 3200);
  add_ln<<<3200, 128, 0, stream>>>(x, tmp, g1, b1, x1);
  // ---- cross attention ----
  gemm3<<<dim3(8, 50), blk, 0, stream>>>(x1, WT[4], WT[4], WT[4],
                                         bq_c, bq_c, bq_c, Qc, Qc, Qc, 3200);
  gemm3<<<dim3(16, 192), blk, 0, stream>>>(cross, WT[5], WT[6], WT[6],
                                           bk_c, bv_c, bv_c, Kc, Vc, Vc, 12288);
  attn_scores<96><<<dim3(8, 128), blk, 0, stream>>>(Qc, Kc, Pc);
  attn_out<96><<<dim3(8, 128), blk, 0, stream>>>(Pc, Vc, attnc);
  gemm3<<<dim3(8, 50), blk, 0, stream>>>(attnc, WT[7], WT[7], WT[7],
                                         bo_c, bo_c, bo_c, tmp2, tmp2, tmp2, 3200);
  add_ln<<<3200, 128, 0, stream>>>(x1, tmp2, g2, b2, x2);
  // ---- LSTM over feature axis ----
  prep_x0r<<<128, 256, 0, stream>>>(x2, X0b);
  lstm_pipeline<<<NLAY * NGRP, 256, 0, stream>>>(X0b, youtb, ringb, ctr, ctr + 512,
                                                 Wih, Whh, bih, bhh);
  // ---- pointwise conv over channels + final LN ----
  transpose_dl<<<128, 256, 0, stream>>>(youtb, ytb);
  gemm3<<<dim3(8, 50), blk, 0, stream>>>(ytb, WT[8], WT[8], WT[8],
                                         bc, bc, bc, fy, fy, fy, 3200);
  add_ln<<<3200, 128, 0, stream>>>(x2, fy, g3, b3, out);
}